// Round 3
// baseline (20.136 us; speedup 1.0000x reference)
//
#include <hip/hip_runtime.h>

#define GSZ   97
#define NPTS  (GSZ * GSZ)
#define DVOL  150
#define HVOL  512
#define WVOL  512
#define TILE  16
#define HALO  2
#define SPAN  (TILE + 2 * HALO)          // 20
#define NTILE ((GSZ + TILE - 1) / TILE)  // 7

// LDS staging box (per channel), sized for pn=(1,1,0.25)-class planes with
// +/-1 voxel margin; runtime-checked with fallback to direct global path.
#define SX 20
#define SY 20
#define SZ 23

struct Basis {
    float pvx, pvy, pvz;
    float pwx, pwy, pwz;
    float nx,  ny,  nz;
    float ox,  oy,  oz;
};

__global__ __launch_bounds__(512)
void planar_tile_kernel(const float* __restrict__ f,
                        const float* __restrict__ pn,
                        const float* __restrict__ org,
                        float* __restrict__ out)
{
    __shared__ float sbox[3][SZ][SY][SX];        // 110.4 KB
    __shared__ float spol[SPAN][SPAN][3];        // 4.8 KB

    const int r0 = blockIdx.y * TILE;
    const int c0 = blockIdx.x * TILE;
    const int tid = threadIdx.x;

    // ---- plane basis (uniform across block; broadcast loads) ----
    Basis B;
    {
        float n0 = pn[0], n1 = pn[1], n2 = pn[2];
        const float nrm = sqrtf(n0 * n0 + n1 * n1 + n2 * n2);
        n0 /= nrm; n1 /= nrm; n2 /= nrm;
        const float beta = 1.0f / sqrtf(1.0f - n2 * n2);
        B.pvx = -n1 * beta; B.pvy = n0 * beta; B.pvz = 0.0f;
        B.pwx = -n2 * B.pvy; B.pwy = n2 * B.pvx; B.pwz = 1.0f / beta;
        B.nx = n0; B.ny = n1; B.nz = n2;
        B.ox = org[0]; B.oy = org[1]; B.oz = org[2];
    }

    // ---- bounding box of this block's patch sample positions ----
    // ix = px * W/(W-1+eps) - 0.5 (affine in gv, gw); same for iy, iz.
    const float EPSF = 1e-8f;
    const float xsc = (float)WVOL / ((float)WVOL - 1.0f + EPSF);
    const float ysc = (float)HVOL / ((float)HVOL - 1.0f + EPSF);
    const float zsc = (float)DVOL / ((float)DVOL - 1.0f + EPSF);

    const float gvlo = (float)(c0 - HALO - 48);
    const float gvhi = (float)(c0 + TILE + HALO - 1 - 48);
    const float gwlo = (float)(r0 - HALO - 48);
    const float gwhi = (float)(r0 + TILE + HALO - 1 - 48);

    int xmin, ymin, zmin, sx, sy, sz;
    {
        const float avx = B.pvx * xsc, awx = B.pwx * xsc, bx = B.ox * xsc - 0.5f;
        const float avy = B.pvy * ysc, awy = B.pwy * ysc, by = B.oy * ysc - 0.5f;
        const float avz = B.pvz * zsc, awz = B.pwz * zsc, bz = B.oz * zsc - 0.5f;

        float x00 = gvlo * avx + gwlo * awx + bx, x01 = gvlo * avx + gwhi * awx + bx;
        float x10 = gvhi * avx + gwlo * awx + bx, x11 = gvhi * avx + gwhi * awx + bx;
        float y00 = gvlo * avy + gwlo * awy + by, y01 = gvlo * avy + gwhi * awy + by;
        float y10 = gvhi * avy + gwlo * awy + by, y11 = gvhi * avy + gwhi * awy + by;
        float z00 = gvlo * avz + gwlo * awz + bz, z01 = gvlo * avz + gwhi * awz + bz;
        float z10 = gvhi * avz + gwlo * awz + bz, z11 = gvhi * avz + gwhi * awz + bz;

        const float M = 0.01f;  // margin vs chain-arithmetic rounding
        const float ixmin = fminf(fminf(x00, x01), fminf(x10, x11)) - M;
        const float ixmax = fmaxf(fmaxf(x00, x01), fmaxf(x10, x11)) + M;
        const float iymin = fminf(fminf(y00, y01), fminf(y10, y11)) - M;
        const float iymax = fmaxf(fmaxf(y00, y01), fmaxf(y10, y11)) + M;
        const float izmin = fminf(fminf(z00, z01), fminf(z10, z11)) - M;
        const float izmax = fmaxf(fmaxf(z00, z01), fmaxf(z10, z11)) + M;

        xmin = min(max((int)floorf(ixmin), 0), WVOL - 1);
        ymin = min(max((int)floorf(iymin), 0), HVOL - 1);
        zmin = min(max((int)floorf(izmin), 0), DVOL - 1);
        const int xmax = min(max((int)floorf(ixmax) + 1, 0), WVOL - 1);
        const int ymax = min(max((int)floorf(iymax) + 1, 0), HVOL - 1);
        const int zmax = min(max((int)floorf(izmax) + 1, 0), DVOL - 1);
        sx = xmax - xmin + 1; sy = ymax - ymin + 1; sz = zmax - zmin + 1;
    }
    const bool useLds = (sx <= SX) && (sy <= SY) && (sz <= SZ);

    const int cstride = DVOL * HVOL * WVOL;

    // ---- stage box into LDS (coalesced, x-fastest) ----
    if (useLds) {
        for (int i = tid; i < 3 * SZ * SY * SX; i += 512) {
            const int lx = i % SX;
            int t = i / SX;
            const int ly = t % SY;
            t /= SY;
            const int lz = t % SZ;
            const int ch = t / SZ;
            const int gx = min(xmin + lx, WVOL - 1);
            const int gy = min(ymin + ly, HVOL - 1);
            const int gz = min(zmin + lz, DVOL - 1);
            sbox[ch][lz][ly][lx] = f[ch * cstride + (gz * HVOL + gy) * WVOL + gx];
        }
        __syncthreads();
    }

    // ---- phase 1: evaluate f_pol on the 20x20 patch (one eval/point) ----
    for (int e = tid; e < SPAN * SPAN; e += 512) {
        const int sr = e / SPAN;
        const int sc = e - sr * SPAN;
        const int gh = r0 - HALO + sr;
        const int gwc = c0 - HALO + sc;
        if (gh < 0 || gh >= GSZ || gwc < 0 || gwc >= GSZ) continue;

        const float gv = (float)(gwc - 48);
        const float gw = (float)(gh - 48);

        // identical arithmetic chain to reference
        const float px = gv * B.pvx + gw * B.pwx + B.ox;
        const float py = gv * B.pvy + gw * B.pwy + B.oy;
        const float pz = gv * B.pvz + gw * B.pwz + B.oz;
        const float gnx = px * (2.0f / ((float)WVOL - 1.0f + EPSF)) - 1.0f;
        const float gny = py * (2.0f / ((float)HVOL - 1.0f + EPSF)) - 1.0f;
        const float gnz = pz * (2.0f / ((float)DVOL - 1.0f + EPSF)) - 1.0f;
        const float ix = ((gnx + 1.0f) * (float)WVOL - 1.0f) * 0.5f;
        const float iy = ((gny + 1.0f) * (float)HVOL - 1.0f) * 0.5f;
        const float iz = ((gnz + 1.0f) * (float)DVOL - 1.0f) * 0.5f;

        const float x0f = floorf(ix), y0f = floorf(iy), z0f = floorf(iz);
        const float wx = ix - x0f, wy = iy - y0f, wz = iz - z0f;
        const int x0 = (int)x0f, y0 = (int)y0f, z0 = (int)z0f;

        float acc0 = 0.0f, acc1 = 0.0f, acc2 = 0.0f;
#pragma unroll
        for (int dz = 0; dz < 2; ++dz) {
            const float wgz = dz ? wz : 1.0f - wz;
            const int zc = z0 + dz;
            const bool vz = (zc >= 0) && (zc < DVOL);
            const int zs = min(max(zc, 0), DVOL - 1);
#pragma unroll
            for (int dy = 0; dy < 2; ++dy) {
                const float wgy = dy ? wy : 1.0f - wy;
                const int yc = y0 + dy;
                const bool vy = (yc >= 0) && (yc < HVOL);
                const int ys = min(max(yc, 0), HVOL - 1);
#pragma unroll
                for (int dx = 0; dx < 2; ++dx) {
                    const float wgx = dx ? wx : 1.0f - wx;
                    const int xc = x0 + dx;
                    const bool vx = (xc >= 0) && (xc < WVOL);
                    const int xs = min(max(xc, 0), WVOL - 1);
                    const float wgt =
                        wgz * wgy * wgx * ((vz && vy && vx) ? 1.0f : 0.0f);
                    float v0, v1, v2;
                    if (useLds) {
                        const int lx = xs - xmin, lyy = ys - ymin, lzz = zs - zmin;
                        v0 = sbox[0][lzz][lyy][lx];
                        v1 = sbox[1][lzz][lyy][lx];
                        v2 = sbox[2][lzz][lyy][lx];
                    } else {
                        const int base = (zs * HVOL + ys) * WVOL + xs;
                        v0 = f[base];
                        v1 = f[base + cstride];
                        v2 = f[base + 2 * cstride];
                    }
                    acc0 += v0 * wgt;
                    acc1 += v1 * wgt;
                    acc2 += v2 * wgt;
                }
            }
        }

        const float p0 = acc0 * B.pvx + acc1 * B.pvy + acc2 * B.pvz;
        const float p1 = acc0 * B.pwx + acc1 * B.pwy + acc2 * B.pwz;
        const float p2 = acc0 * B.nx  + acc1 * B.ny  + acc2 * B.nz;

        const float r = sqrtf(gv * gv + gw * gw);
        const float s = (r > 0.0f) ? gw / r : 0.0f;
        const float c = (r > 0.0f) ? gv / r : 1.0f;
        spol[sr][sc][0] =  c * p0 + s * p1;
        spol[sr][sc][1] = -s * p0 + c * p1;
        spol[sr][sc][2] =  p2;

        if (gh >= r0 && gh < r0 + TILE && gwc >= c0 && gwc < c0 + TILE) {
            const int idx = gh * GSZ + gwc;
            out[0 * NPTS + idx] = p0;
            out[1 * NPTS + idx] = p1;
            out[2 * NPTS + idx] = p2;
        }
    }

    __syncthreads();

    // ---- phase 2: gradients from LDS, rotate, store ----
    if (tid >= TILE * TILE) return;
    const int lr = tid >> 4;
    const int lc = tid & 15;
    const int h = r0 + lr;
    const int w = c0 + lc;
    if (h >= GSZ || w >= GSZ) return;

    const int sr = lr + HALO;
    const int sc = lc + HALO;

    float gxv[3], gyv[3];

    if (w == 0) {
#pragma unroll
        for (int i = 0; i < 3; ++i)
            gxv[i] = -1.5f * spol[sr][2][i] + 2.0f * spol[sr][3][i]
                     - 0.5f * spol[sr][4][i];
    } else if (w == GSZ - 1) {
        const int b = (GSZ - 1) - c0 + HALO;
#pragma unroll
        for (int i = 0; i < 3; ++i)
            gxv[i] = 1.5f * spol[sr][b][i] - 2.0f * spol[sr][b - 1][i]
                     + 0.5f * spol[sr][b - 2][i];
    } else {
#pragma unroll
        for (int i = 0; i < 3; ++i)
            gxv[i] = 0.5f * (spol[sr][sc + 1][i] - spol[sr][sc - 1][i]);
    }

    if (h == 0) {
#pragma unroll
        for (int i = 0; i < 3; ++i)
            gyv[i] = -1.5f * spol[2][sc][i] + 2.0f * spol[3][sc][i]
                     - 0.5f * spol[4][sc][i];
    } else if (h == GSZ - 1) {
        const int b = (GSZ - 1) - r0 + HALO;
#pragma unroll
        for (int i = 0; i < 3; ++i)
            gyv[i] = 1.5f * spol[b][sc][i] - 2.0f * spol[b - 1][sc][i]
                     + 0.5f * spol[b - 2][sc][i];
    } else {
#pragma unroll
        for (int i = 0; i < 3; ++i)
            gyv[i] = 0.5f * (spol[sr + 1][sc][i] - spol[sr - 1][sc][i]);
    }

    const float gv = (float)(w - 48);
    const float gw = (float)(h - 48);
    const float r = sqrtf(gv * gv + gw * gw);
    const float s = (r > 0.0f) ? gw / r : 0.0f;
    const float c = (r > 0.0f) ? gv / r : 1.0f;

    const int idx = h * GSZ + w;
    float* __restrict__ o2 = out + 3 * NPTS;
#pragma unroll
    for (int i = 0; i < 3; ++i) {
        o2[(0 * 3 + i) * NPTS + idx] =  c * gxv[i] + s * gyv[i];
        o2[(1 * 3 + i) * NPTS + idx] = -s * gxv[i] + c * gyv[i];
        o2[(2 * 3 + i) * NPTS + idx] = 0.0f;
    }
}

extern "C" void kernel_launch(void* const* d_in, const int* in_sizes, int n_in,
                              void* d_out, int out_size, void* d_ws, size_t ws_size,
                              hipStream_t stream) {
    const float* f   = (const float*)d_in[0];
    const float* pn  = (const float*)d_in[1];
    const float* org = (const float*)d_in[2];
    float* out = (float*)d_out;

    dim3 grid(NTILE, NTILE);
    planar_tile_kernel<<<grid, 512, 0, stream>>>(f, pn, org, out);
}

// Round 4
// 10.026 us; speedup vs baseline: 2.0083x; 2.0083x over previous
//
#include <hip/hip_runtime.h>

#define GSZ   97
#define NPTS  (GSZ * GSZ)
#define DVOL  150
#define HVOL  512
#define WVOL  512
#define TILE  8
#define HALO  2
#define SPAN  (TILE + 2 * HALO)          // 12
#define NTILE ((GSZ + TILE - 1) / TILE)  // 13

struct Basis {
    float pvx, pvy, pvz;
    float pwx, pwy, pwz;
    float nx,  ny,  nz;
    float ox,  oy,  oz;
};

__global__ __launch_bounds__(256)
void planar_tile_kernel(const float* __restrict__ f,
                        const float* __restrict__ pn,
                        const float* __restrict__ org,
                        float* __restrict__ out)
{
    __shared__ float spol[SPAN][SPAN][3];   // 1.7 KB

    const int r0 = blockIdx.y * TILE;
    const int c0 = blockIdx.x * TILE;
    const int tid = threadIdx.x;

    // ---- plane basis (uniform across block; broadcast loads) ----
    Basis B;
    {
        float n0 = pn[0], n1 = pn[1], n2 = pn[2];
        const float nrm = sqrtf(n0 * n0 + n1 * n1 + n2 * n2);
        n0 /= nrm; n1 /= nrm; n2 /= nrm;
        const float beta = 1.0f / sqrtf(1.0f - n2 * n2);
        B.pvx = -n1 * beta; B.pvy = n0 * beta; B.pvz = 0.0f;
        B.pwx = -n2 * B.pvy; B.pwy = n2 * B.pvx; B.pwz = 1.0f / beta;
        B.nx = n0; B.ny = n1; B.nz = n2;
        B.ox = org[0]; B.oy = org[1]; B.oz = org[2];
    }

    const float EPSF = 1e-8f;
    const int cstride = DVOL * HVOL * WVOL;

    // ---- phase 1: evaluate f_pol on the 12x12 patch (one eval/point) ----
    // 144 evals < 256 threads: single divergence-free round.
    if (tid < SPAN * SPAN) {
        const int sr = tid / SPAN;
        const int sc = tid - sr * SPAN;
        const int gh = r0 - HALO + sr;
        const int gwc = c0 - HALO + sc;
        if (gh >= 0 && gh < GSZ && gwc >= 0 && gwc < GSZ) {
            const float gv = (float)(gwc - 48);
            const float gw = (float)(gh - 48);

            // identical arithmetic chain to reference
            const float px = gv * B.pvx + gw * B.pwx + B.ox;
            const float py = gv * B.pvy + gw * B.pwy + B.oy;
            const float pz = gv * B.pvz + gw * B.pwz + B.oz;
            const float gnx = px * (2.0f / ((float)WVOL - 1.0f + EPSF)) - 1.0f;
            const float gny = py * (2.0f / ((float)HVOL - 1.0f + EPSF)) - 1.0f;
            const float gnz = pz * (2.0f / ((float)DVOL - 1.0f + EPSF)) - 1.0f;
            const float ix = ((gnx + 1.0f) * (float)WVOL - 1.0f) * 0.5f;
            const float iy = ((gny + 1.0f) * (float)HVOL - 1.0f) * 0.5f;
            const float iz = ((gnz + 1.0f) * (float)DVOL - 1.0f) * 0.5f;

            const float x0f = floorf(ix), y0f = floorf(iy), z0f = floorf(iz);
            const float wx = ix - x0f, wy = iy - y0f, wz = iz - z0f;
            const int x0 = (int)x0f, y0 = (int)y0f, z0 = (int)z0f;

            float acc0 = 0.0f, acc1 = 0.0f, acc2 = 0.0f;
#pragma unroll
            for (int dz = 0; dz < 2; ++dz) {
                const float wgz = dz ? wz : 1.0f - wz;
                const int zc = z0 + dz;
                const bool vz = (zc >= 0) && (zc < DVOL);
                const int zs = min(max(zc, 0), DVOL - 1);
#pragma unroll
                for (int dy = 0; dy < 2; ++dy) {
                    const float wgy = dy ? wy : 1.0f - wy;
                    const int yc = y0 + dy;
                    const bool vy = (yc >= 0) && (yc < HVOL);
                    const int ys = min(max(yc, 0), HVOL - 1);
#pragma unroll
                    for (int dx = 0; dx < 2; ++dx) {
                        const float wgx = dx ? wx : 1.0f - wx;
                        const int xc = x0 + dx;
                        const bool vx = (xc >= 0) && (xc < WVOL);
                        const int xs = min(max(xc, 0), WVOL - 1);
                        const float wgt =
                            wgz * wgy * wgx * ((vz && vy && vx) ? 1.0f : 0.0f);
                        const int base = (zs * HVOL + ys) * WVOL + xs;
                        acc0 += f[base] * wgt;
                        acc1 += f[base + cstride] * wgt;
                        acc2 += f[base + 2 * cstride] * wgt;
                    }
                }
            }

            const float p0 = acc0 * B.pvx + acc1 * B.pvy + acc2 * B.pvz;
            const float p1 = acc0 * B.pwx + acc1 * B.pwy + acc2 * B.pwz;
            const float p2 = acc0 * B.nx  + acc1 * B.ny  + acc2 * B.nz;

            const float r = sqrtf(gv * gv + gw * gw);
            const float s = (r > 0.0f) ? gw / r : 0.0f;
            const float c = (r > 0.0f) ? gv / r : 1.0f;
            spol[sr][sc][0] =  c * p0 + s * p1;
            spol[sr][sc][1] = -s * p0 + c * p1;
            spol[sr][sc][2] =  p2;

            if (gh >= r0 && gh < r0 + TILE && gwc >= c0 && gwc < c0 + TILE) {
                const int idx = gh * GSZ + gwc;
                out[0 * NPTS + idx] = p0;
                out[1 * NPTS + idx] = p1;
                out[2 * NPTS + idx] = p2;
            }
        }
    }

    __syncthreads();

    // ---- phase 2: gradients from LDS, rotate, store ----
    if (tid >= TILE * TILE) return;
    const int lr = tid >> 3;
    const int lc = tid & 7;
    const int h = r0 + lr;
    const int w = c0 + lc;
    if (h >= GSZ || w >= GSZ) return;

    const int sr = lr + HALO;
    const int sc = lc + HALO;

    float gxv[3], gyv[3];

    if (w == 0) {
#pragma unroll
        for (int i = 0; i < 3; ++i)
            gxv[i] = -1.5f * spol[sr][2][i] + 2.0f * spol[sr][3][i]
                     - 0.5f * spol[sr][4][i];
    } else if (w == GSZ - 1) {
        const int b = (GSZ - 1) - c0 + HALO;
#pragma unroll
        for (int i = 0; i < 3; ++i)
            gxv[i] = 1.5f * spol[sr][b][i] - 2.0f * spol[sr][b - 1][i]
                     + 0.5f * spol[sr][b - 2][i];
    } else {
#pragma unroll
        for (int i = 0; i < 3; ++i)
            gxv[i] = 0.5f * (spol[sr][sc + 1][i] - spol[sr][sc - 1][i]);
    }

    if (h == 0) {
#pragma unroll
        for (int i = 0; i < 3; ++i)
            gyv[i] = -1.5f * spol[2][sc][i] + 2.0f * spol[3][sc][i]
                     - 0.5f * spol[4][sc][i];
    } else if (h == GSZ - 1) {
        const int b = (GSZ - 1) - r0 + HALO;
#pragma unroll
        for (int i = 0; i < 3; ++i)
            gyv[i] = 1.5f * spol[b][sc][i] - 2.0f * spol[b - 1][sc][i]
                     + 0.5f * spol[b - 2][sc][i];
    } else {
#pragma unroll
        for (int i = 0; i < 3; ++i)
            gyv[i] = 0.5f * (spol[sr + 1][sc][i] - spol[sr - 1][sc][i]);
    }

    const float gv = (float)(w - 48);
    const float gw = (float)(h - 48);
    const float r = sqrtf(gv * gv + gw * gw);
    const float s = (r > 0.0f) ? gw / r : 0.0f;
    const float c = (r > 0.0f) ? gv / r : 1.0f;

    const int idx = h * GSZ + w;
    float* __restrict__ o2 = out + 3 * NPTS;
#pragma unroll
    for (int i = 0; i < 3; ++i) {
        o2[(0 * 3 + i) * NPTS + idx] =  c * gxv[i] + s * gyv[i];
        o2[(1 * 3 + i) * NPTS + idx] = -s * gxv[i] + c * gyv[i];
        o2[(2 * 3 + i) * NPTS + idx] = 0.0f;
    }
}

extern "C" void kernel_launch(void* const* d_in, const int* in_sizes, int n_in,
                              void* d_out, int out_size, void* d_ws, size_t ws_size,
                              hipStream_t stream) {
    const float* f   = (const float*)d_in[0];
    const float* pn  = (const float*)d_in[1];
    const float* org = (const float*)d_in[2];
    float* out = (float*)d_out;

    dim3 grid(NTILE, NTILE);
    planar_tile_kernel<<<grid, 256, 0, stream>>>(f, pn, org, out);
}

// Round 5
// 10.017 us; speedup vs baseline: 2.0101x; 1.0009x over previous
//
#include <hip/hip_runtime.h>

#define GSZ   97
#define NPTS  (GSZ * GSZ)
#define DVOL  150
#define HVOL  512
#define WVOL  512
#define TILE  8
#define HALO  2
#define SPAN  (TILE + 2 * HALO)          // 12
#define NTILE ((GSZ + TILE - 1) / TILE)  // 13

struct Basis {
    float pvx, pvy, pvz;
    float pwx, pwy, pwz;
    float nx,  ny,  nz;
    float ox,  oy,  oz;
};

__global__ __launch_bounds__(256)
void planar_tile_kernel(const float* __restrict__ f,
                        const float* __restrict__ pn,
                        const float* __restrict__ org,
                        float* __restrict__ out)
{
    __shared__ float spol[SPAN][SPAN][3];   // 1.7 KB

    const int r0 = blockIdx.y * TILE;
    const int c0 = blockIdx.x * TILE;
    const int tid = threadIdx.x;

    // ---- plane basis (uniform across block; broadcast loads) ----
    Basis B;
    {
        float n0 = pn[0], n1 = pn[1], n2 = pn[2];
        const float nrm = sqrtf(n0 * n0 + n1 * n1 + n2 * n2);
        n0 /= nrm; n1 /= nrm; n2 /= nrm;
        const float beta = 1.0f / sqrtf(1.0f - n2 * n2);
        B.pvx = -n1 * beta; B.pvy = n0 * beta; B.pvz = 0.0f;
        B.pwx = -n2 * B.pvy; B.pwy = n2 * B.pvx; B.pwz = 1.0f / beta;
        B.nx = n0; B.ny = n1; B.nz = n2;
        B.ox = org[0]; B.oy = org[1]; B.oz = org[2];
    }

    const float EPSF = 1e-8f;
    const int cstride = DVOL * HVOL * WVOL;

    // ---- phase 1: evaluate f_pol on the 12x12 patch (one eval/point) ----
    if (tid < SPAN * SPAN) {
        const int sr = tid / SPAN;
        const int sc = tid - sr * SPAN;
        const int gh = r0 - HALO + sr;
        const int gwc = c0 - HALO + sc;
        if (gh >= 0 && gh < GSZ && gwc >= 0 && gwc < GSZ) {
            const float gv = (float)(gwc - 48);
            const float gw = (float)(gh - 48);

            // identical arithmetic chain to reference
            const float px = gv * B.pvx + gw * B.pwx + B.ox;
            const float py = gv * B.pvy + gw * B.pwy + B.oy;
            const float pz = gv * B.pvz + gw * B.pwz + B.oz;
            const float gnx = px * (2.0f / ((float)WVOL - 1.0f + EPSF)) - 1.0f;
            const float gny = py * (2.0f / ((float)HVOL - 1.0f + EPSF)) - 1.0f;
            const float gnz = pz * (2.0f / ((float)DVOL - 1.0f + EPSF)) - 1.0f;
            const float ix = ((gnx + 1.0f) * (float)WVOL - 1.0f) * 0.5f;
            const float iy = ((gny + 1.0f) * (float)HVOL - 1.0f) * 0.5f;
            const float iz = ((gnz + 1.0f) * (float)DVOL - 1.0f) * 0.5f;

            const float x0f = floorf(ix), y0f = floorf(iy), z0f = floorf(iz);
            const float wx = ix - x0f, wy = iy - y0f, wz = iz - z0f;
            const int x0 = (int)x0f, y0 = (int)y0f, z0 = (int)z0f;

            const bool xpair = (x0 >= 0) && (x0 + 1 < WVOL);

            float acc0 = 0.0f, acc1 = 0.0f, acc2 = 0.0f;
#pragma unroll
            for (int dz = 0; dz < 2; ++dz) {
                const float wgz = dz ? wz : 1.0f - wz;
                const int zc = z0 + dz;
                const bool vz = (zc >= 0) && (zc < DVOL);
                const int zs = min(max(zc, 0), DVOL - 1);
#pragma unroll
                for (int dy = 0; dy < 2; ++dy) {
                    const float wgy = dy ? wy : 1.0f - wy;
                    const int yc = y0 + dy;
                    const bool vy = (yc >= 0) && (yc < HVOL);
                    const int ys = min(max(yc, 0), HVOL - 1);
                    const float wzy = wgz * wgy;
                    const int rowbase = (zs * HVOL + ys) * WVOL;

                    if (xpair) {
                        // one float2 per channel covers both x-taps
                        const float vf = (vz && vy) ? 1.0f : 0.0f;
                        const float w0 = wzy * (1.0f - wx) * vf;
                        const float w1 = wzy * wx * vf;
                        const int base = rowbase + x0;
                        float2 p0, p1, p2;
                        __builtin_memcpy(&p0, f + base, sizeof(float2));
                        __builtin_memcpy(&p1, f + base + cstride, sizeof(float2));
                        __builtin_memcpy(&p2, f + base + 2 * cstride, sizeof(float2));
                        acc0 += p0.x * w0; acc0 += p0.y * w1;
                        acc1 += p1.x * w0; acc1 += p1.y * w1;
                        acc2 += p2.x * w0; acc2 += p2.y * w1;
                    } else {
#pragma unroll
                        for (int dx = 0; dx < 2; ++dx) {
                            const float wgx = dx ? wx : 1.0f - wx;
                            const int xc = x0 + dx;
                            const bool vx = (xc >= 0) && (xc < WVOL);
                            const int xs = min(max(xc, 0), WVOL - 1);
                            const float wgt =
                                wzy * wgx * ((vz && vy && vx) ? 1.0f : 0.0f);
                            const int base = rowbase + xs;
                            acc0 += f[base] * wgt;
                            acc1 += f[base + cstride] * wgt;
                            acc2 += f[base + 2 * cstride] * wgt;
                        }
                    }
                }
            }

            const float p0 = acc0 * B.pvx + acc1 * B.pvy + acc2 * B.pvz;
            const float p1 = acc0 * B.pwx + acc1 * B.pwy + acc2 * B.pwz;
            const float p2 = acc0 * B.nx  + acc1 * B.ny  + acc2 * B.nz;

            const float r = sqrtf(gv * gv + gw * gw);
            const float s = (r > 0.0f) ? gw / r : 0.0f;
            const float c = (r > 0.0f) ? gv / r : 1.0f;
            spol[sr][sc][0] =  c * p0 + s * p1;
            spol[sr][sc][1] = -s * p0 + c * p1;
            spol[sr][sc][2] =  p2;

            if (gh >= r0 && gh < r0 + TILE && gwc >= c0 && gwc < c0 + TILE) {
                const int idx = gh * GSZ + gwc;
                out[0 * NPTS + idx] = p0;
                out[1 * NPTS + idx] = p1;
                out[2 * NPTS + idx] = p2;
            }
        }
    }

    __syncthreads();

    // ---- phase 2: gradients from LDS, rotate, store ----
    if (tid >= TILE * TILE) return;
    const int lr = tid >> 3;
    const int lc = tid & 7;
    const int h = r0 + lr;
    const int w = c0 + lc;
    if (h >= GSZ || w >= GSZ) return;

    const int sr = lr + HALO;
    const int sc = lc + HALO;

    float gxv[3], gyv[3];

    if (w == 0) {
#pragma unroll
        for (int i = 0; i < 3; ++i)
            gxv[i] = -1.5f * spol[sr][2][i] + 2.0f * spol[sr][3][i]
                     - 0.5f * spol[sr][4][i];
    } else if (w == GSZ - 1) {
        const int b = (GSZ - 1) - c0 + HALO;
#pragma unroll
        for (int i = 0; i < 3; ++i)
            gxv[i] = 1.5f * spol[sr][b][i] - 2.0f * spol[sr][b - 1][i]
                     + 0.5f * spol[sr][b - 2][i];
    } else {
#pragma unroll
        for (int i = 0; i < 3; ++i)
            gxv[i] = 0.5f * (spol[sr][sc + 1][i] - spol[sr][sc - 1][i]);
    }

    if (h == 0) {
#pragma unroll
        for (int i = 0; i < 3; ++i)
            gyv[i] = -1.5f * spol[2][sc][i] + 2.0f * spol[3][sc][i]
                     - 0.5f * spol[4][sc][i];
    } else if (h == GSZ - 1) {
        const int b = (GSZ - 1) - r0 + HALO;
#pragma unroll
        for (int i = 0; i < 3; ++i)
            gyv[i] = 1.5f * spol[b][sc][i] - 2.0f * spol[b - 1][sc][i]
                     + 0.5f * spol[b - 2][sc][i];
    } else {
#pragma unroll
        for (int i = 0; i < 3; ++i)
            gyv[i] = 0.5f * (spol[sr + 1][sc][i] - spol[sr - 1][sc][i]);
    }

    const float gv = (float)(w - 48);
    const float gw = (float)(h - 48);
    const float r = sqrtf(gv * gv + gw * gw);
    const float s = (r > 0.0f) ? gw / r : 0.0f;
    const float c = (r > 0.0f) ? gv / r : 1.0f;

    const int idx = h * GSZ + w;
    float* __restrict__ o2 = out + 3 * NPTS;
#pragma unroll
    for (int i = 0; i < 3; ++i) {
        o2[(0 * 3 + i) * NPTS + idx] =  c * gxv[i] + s * gyv[i];
        o2[(1 * 3 + i) * NPTS + idx] = -s * gxv[i] + c * gyv[i];
        o2[(2 * 3 + i) * NPTS + idx] = 0.0f;
    }
}

extern "C" void kernel_launch(void* const* d_in, const int* in_sizes, int n_in,
                              void* d_out, int out_size, void* d_ws, size_t ws_size,
                              hipStream_t stream) {
    const float* f   = (const float*)d_in[0];
    const float* pn  = (const float*)d_in[1];
    const float* org = (const float*)d_in[2];
    float* out = (float*)d_out;

    dim3 grid(NTILE, NTILE);
    planar_tile_kernel<<<grid, 256, 0, stream>>>(f, pn, org, out);
}